// Round 8
// baseline (123.329 us; speedup 1.0000x reference)
//
#include <hip/hip_runtime.h>
#include <hip/hip_bf16.h>

typedef unsigned short ushort_t;
typedef unsigned int uint_t;
using f32x4  = __attribute__((ext_vector_type(4))) float;
using short8 = __attribute__((ext_vector_type(8))) short;

#define NN 8192
#define INVLN2 1.4426950408889634f

__device__ __forceinline__ ushort_t f2bf(float f) {
  uint_t u = __builtin_bit_cast(uint_t, f);
  u += 0x7FFFu + ((u >> 16) & 1u);   // RNE
  return (ushort_t)(u >> 16);
}

__device__ __forceinline__ float fexp2(float x) {
  float r; asm("v_exp_f32 %0, %1" : "=v"(r) : "v"(x)); return r;
}

// ---------------------------------------------------------------------------
// K1: Xp = X @ W  -> XpT bf16 [2*64][8192] (row = h*64+c), x0[N][2], x1T[2][N]
// x0/x1 are pre-scaled by 1/ln2 (lrelu is positively homogeneous, so
// exp(lrelu(s)) == exp2(lrelu(s/ln2)) with s/ln2 = x0'+x1').
// ---------------------------------------------------------------------------
__global__ __launch_bounds__(256, 2) void k1_project(
    const float* __restrict__ X, const float* __restrict__ W,
    const float* __restrict__ attn,
    ushort_t* __restrict__ XpT, float* __restrict__ x0g, float* __restrict__ x1g)
{
  __shared__ float    Xl[32][128];      // 16 KB
  __shared__ ushort_t XpL[128][56];     // 14 KB
  __shared__ float    P0[128][33];
  __shared__ float    P1[128][33];
  const int t  = threadIdx.x;
  const int nb = blockIdx.x * 32;

  #pragma unroll
  for (int r = 0; r < 4; ++r) {
    int chunk = r * 256 + t;
    ((float4*)(&Xl[0][0]))[chunk] = ((const float4*)(X + (size_t)nb * 128))[chunk];
  }
  __syncthreads();

  const int p = t & 127;
  const int g = t >> 7;
  const int h = p & 1, c = p >> 1;

  float acc[16];
  #pragma unroll
  for (int n = 0; n < 16; ++n) acc[n] = 0.f;

  for (int jc = 0; jc < 4; ++jc) {
    float wreg[32];
    #pragma unroll
    for (int jj = 0; jj < 32; ++jj) wreg[jj] = W[(jc * 32 + jj) * 128 + p];
    #pragma unroll
    for (int n = 0; n < 16; ++n) {
      const float4* xr = (const float4*)(&Xl[g * 16 + n][jc * 32]);
      float s = acc[n];
      #pragma unroll
      for (int q = 0; q < 8; ++q) {
        float4 xv = xr[q];
        s += xv.x * wreg[q*4+0] + xv.y * wreg[q*4+1] + xv.z * wreg[q*4+2] + xv.w * wreg[q*4+3];
      }
      acc[n] = s;
    }
  }

  const float a0 = attn[p] * INVLN2;        // fold 1/ln2 into attention vecs
  const float a1 = attn[128 + p] * INVLN2;
  const int   row = h * 64 + c;
  #pragma unroll
  for (int n = 0; n < 16; ++n) {
    P0[p][g * 16 + n]  = acc[n] * a0;
    P1[p][g * 16 + n]  = acc[n] * a1;
    XpL[row][g * 16 + n] = f2bf(acc[n]);
  }
  __syncthreads();

  if (t < 128) {
    ushort_t* dst = XpT + (size_t)t * NN + nb;
    const uint4* src = (const uint4*)(&XpL[t][0]);
    ((uint4*)dst)[0] = src[0];
    ((uint4*)dst)[1] = src[1];
    ((uint4*)dst)[2] = src[2];
    ((uint4*)dst)[3] = src[3];
  }
  if (t < 64) {
    int node = t >> 1, hh = t & 1;
    float s0 = 0.f, s1 = 0.f;
    #pragma unroll
    for (int cc = 0; cc < 64; ++cc) {
      s0 += P0[cc * 2 + hh][node];
      s1 += P1[cc * 2 + hh][node];
    }
    x0g[(nb + node) * 2 + hh] = s0;
    x1g[hh * NN + nb + node]  = s1;
  }
}

// ---------------------------------------------------------------------------
// K2: one barrier/body, no vmcnt waits. LDS = double-buffered P tile only
// (16 KB). B-frags read directly from L2-resident XpT into registers
// (layout verified in r4). A/B reg sets ping-pong (U/V) at distance 2;
// refills pinned inside barrier-delimited zones by "memory" clobbers.
// 4 waves: hw=w&1 (head), cbh=w>>1 (col half); each wave does both 16-row
// blocks -> 8 MFMA/body. P-compute identical to r3 (verified), with
// v_cvt_pk_bf16_f32 (verified r5) and exp2 (1/ln2 folded in k1).
// ---------------------------------------------------------------------------
__global__ __launch_bounds__(256, 4) void k2_main(
    const float* __restrict__ A, const ushort_t* __restrict__ XpT,
    const float* __restrict__ x0g, const float* __restrict__ x1g,
    float* __restrict__ part, float* __restrict__ denp,
    const int S, const int KS)
{
  __shared__ __align__(16) ushort_t Pl[2 * 64 * 64];   // 16 KB: 2 bufs x [64][64]
  const int t  = threadIdx.x;
  const int b  = blockIdx.x;
  const int rb = b / S, sp = b % S;
  const int ib = rb * 32;
  const int k0 = sp * KS;
  const int lane = t & 63, w = t >> 6;
  const int hw  = w & 1;        // head
  const int cbh = w >> 1;       // col half: cb in {2cbh, 2cbh+1}
  const int pr  = t >> 4;       // P-compute row 0..15
  const int pk  = (t & 15) * 4; // P-compute col offset

  float x0a[2][2];
  #pragma unroll
  for (int ps = 0; ps < 2; ++ps) {
    float2 v = *(const float2*)(x0g + (ib + ps * 16 + pr) * 2);
    x0a[ps][0] = v.x; x0a[ps][1] = v.y;
  }

  // Pl write byte offsets (XOR swizzle ^((row&7)<<4); row&7 == pr&7)
  int plw[2][2];
  #pragma unroll
  for (int ps = 0; ps < 2; ++ps)
    #pragma unroll
    for (int hh = 0; hh < 2; ++hh) {
      int row = hh * 32 + ps * 16 + pr;
      plw[ps][hh] = (row * 128 + pk * 2) ^ ((pr & 7) << 4);
    }

  // A-frag read byte offsets [iwi][ks]
  int aoff[2][2];
  #pragma unroll
  for (int iwi = 0; iwi < 2; ++iwi) {
    int arow = hw * 32 + iwi * 16 + (lane & 15);
    #pragma unroll
    for (int ks = 0; ks < 2; ++ks)
      aoff[iwi][ks] = (arow * 128 + ks * 64 + (lane >> 4) * 16) ^ ((arow & 7) << 4);
  }

  // B-frag pointers [ks][c] (direct from XpT; +tile<<6 at load)
  const ushort_t* Bp00 = XpT + (size_t)(hw * 64 + (cbh * 2 + 0) * 16 + (lane & 15)) * NN + k0 +  0 + (lane >> 4) * 8;
  const ushort_t* Bp01 = XpT + (size_t)(hw * 64 + (cbh * 2 + 1) * 16 + (lane & 15)) * NN + k0 +  0 + (lane >> 4) * 8;
  const ushort_t* Bp10 = Bp00 + 32;
  const ushort_t* Bp11 = Bp01 + 32;

  f32x4 acc[2][2] = {};     // [iwi][c] — constant-indexed after unroll
  float den[2][2] = {};

  const float* Ap0 = A + (size_t)(ib + pr) * NN + k0 + pk;
  const float* Ap1 = A + (size_t)(ib + 16 + pr) * NN + k0 + pk;
  const float* Xq0 = x1g + k0 + pk;
  const float* Xq1 = x1g + NN + k0 + pk;
  const int nt = KS >> 6;          // 32 for S=4 (even)
  const int lastT = nt - 1;

  float4 Ua0, Ua1, Va0, Va1;
  short8 Ub00, Ub01, Ub10, Ub11, Vb00, Vb01, Vb10, Vb11;

#define LDA(a0v, a1v, TILE) { const int kk_ = (TILE) << 6;                   \
    a0v = *(const float4*)(Ap0 + kk_); a1v = *(const float4*)(Ap1 + kk_); }
#define LDB(q00, q01, q10, q11, TILE) { const int kk_ = (TILE) << 6;         \
    q00 = *(const short8*)(Bp00 + kk_); q01 = *(const short8*)(Bp01 + kk_);  \
    q10 = *(const short8*)(Bp10 + kk_); q11 = *(const short8*)(Bp11 + kk_); }

  LDA(Ua0, Ua1, 0) LDB(Ub00, Ub01, Ub10, Ub11, 0)
  LDA(Va0, Va1, 1) LDB(Vb00, Vb01, Vb10, Vb11, 1)

#define KBODY(a0v, a1v, q00, q01, q10, q11, TT)                              \
  {                                                                          \
    const int t_  = (TT);                                                    \
    const int rt_ = (t_ + 2 < nt) ? (t_ + 2) : lastT;                        \
    char* plb = (char*)Pl + (t_ & 1) * 8192;                                 \
    /* x1 JIT (L1 broadcast: 16 lanes/addr) */                               \
    float4 xv0 = *(const float4*)(Xq0 + (t_ << 6));                          \
    float4 xv1 = *(const float4*)(Xq1 + (t_ << 6));                          \
    float aarr[2][4] = {{a0v.x, a0v.y, a0v.z, a0v.w},                        \
                        {a1v.x, a1v.y, a1v.z, a1v.w}};                       \
    float xarr[2][4] = {{xv0.x, xv0.y, xv0.z, xv0.w},                        \
                        {xv1.x, xv1.y, xv1.z, xv1.w}};                       \
    _Pragma("unroll")                                                        \
    for (int ps = 0; ps < 2; ++ps) {                                         \
      _Pragma("unroll")                                                      \
      for (int hh = 0; hh < 2; ++hh) {                                       \
        float pv[4];                                                         \
        _Pragma("unroll")                                                    \
        for (int j = 0; j < 4; ++j) {                                        \
          float s = x0a[ps][hh] + xarr[hh][j];                               \
          float e = fexp2(fmaxf(s, 0.2f * s));                               \
          pv[j] = aarr[ps][j] * e;                                           \
          den[ps][hh] += pv[j];                                              \
        }                                                                    \
        uint_t u0_, u1_;                                                     \
        asm("v_cvt_pk_bf16_f32 %0, %1, %2" : "=v"(u0_) : "v"(pv[0]), "v"(pv[1])); \
        asm("v_cvt_pk_bf16_f32 %0, %1, %2" : "=v"(u1_) : "v"(pv[2]), "v"(pv[3])); \
        uint2 vv_; vv_.x = u0_; vv_.y = u1_;                                 \
        *(uint2*)(plb + plw[ps][hh]) = vv_;                                  \
      }                                                                      \
    }                                                                        \
    /* refill this set's A with tile t+2 (regs just consumed) */             \
    LDA(a0v, a1v, rt_)                                                       \
    asm volatile("s_waitcnt lgkmcnt(0)" ::: "memory");                       \
    __builtin_amdgcn_s_barrier();                                            \
    asm volatile("" ::: "memory");                                           \
    /* MFMA on tile t (B-frags loaded 2 bodies ago) */                       \
    {                                                                        \
      short8 af00 = *(const short8*)(plb + aoff[0][0]);                      \
      short8 af10 = *(const short8*)(plb + aoff[1][0]);                      \
      acc[0][0] = __builtin_amdgcn_mfma_f32_16x16x32_bf16(af00, q00, acc[0][0], 0, 0, 0); \
      acc[0][1] = __builtin_amdgcn_mfma_f32_16x16x32_bf16(af00, q01, acc[0][1], 0, 0, 0); \
      acc[1][0] = __builtin_amdgcn_mfma_f32_16x16x32_bf16(af10, q00, acc[1][0], 0, 0, 0); \
      acc[1][1] = __builtin_amdgcn_mfma_f32_16x16x32_bf16(af10, q01, acc[1][1], 0, 0, 0); \
      short8 af01 = *(const short8*)(plb + aoff[0][1]);                      \
      short8 af11 = *(const short8*)(plb + aoff[1][1]);                      \
      acc[0][0] = __builtin_amdgcn_mfma_f32_16x16x32_bf16(af01, q10, acc[0][0], 0, 0, 0); \
      acc[0][1] = __builtin_amdgcn_mfma_f32_16x16x32_bf16(af01, q11, acc[0][1], 0, 0, 0); \
      acc[1][0] = __builtin_amdgcn_mfma_f32_16x16x32_bf16(af11, q10, acc[1][0], 0, 0, 0); \
      acc[1][1] = __builtin_amdgcn_mfma_f32_16x16x32_bf16(af11, q11, acc[1][1], 0, 0, 0); \
    }                                                                        \
    /* refill this set's B with tile t+2 */                                  \
    LDB(q00, q01, q10, q11, rt_)                                             \
  }

  for (int tt = 0; tt < nt; tt += 2) {
    KBODY(Ua0, Ua1, Ub00, Ub01, Ub10, Ub11, tt)
    KBODY(Va0, Va1, Vb00, Vb01, Vb10, Vb11, tt + 1)
  }
#undef KBODY
#undef LDB
#undef LDA

  // --- den: reduce across 16-lane groups (covers all rows via pr=t>>4) ---
  #pragma unroll
  for (int ps = 0; ps < 2; ++ps) {
    #pragma unroll
    for (int hh = 0; hh < 2; ++hh) {
      float d = den[ps][hh];
      d += __shfl_xor(d, 1, 16);
      d += __shfl_xor(d, 2, 16);
      d += __shfl_xor(d, 4, 16);
      d += __shfl_xor(d, 8, 16);
      if ((t & 15) == 0)
        denp[((size_t)sp * NN + ib + ps * 16 + (t >> 4)) * 2 + hh] = d;
    }
  }

  // --- partial numerators (C/D layout: col=lane&15, row=(lane>>4)*4+r) ---
  float* pbase = part + ((size_t)sp * NN + ib) * 128;
  #pragma unroll
  for (int iwi = 0; iwi < 2; ++iwi)
    #pragma unroll
    for (int c = 0; c < 2; ++c)
      #pragma unroll
      for (int r = 0; r < 4; ++r) {
        int lr  = iwi * 16 + (lane >> 4) * 4 + r;
        int col = (cbh * 2 + c) * 16 + (lane & 15);
        pbase[lr * 128 + hw * 64 + col] = acc[iwi][c][r];
      }
}

// ---------------------------------------------------------------------------
// K3: combine splits, normalize, add bias.
// ---------------------------------------------------------------------------
__global__ __launch_bounds__(256) void k3_finish(
    const float* __restrict__ part, const float* __restrict__ denp,
    const float* __restrict__ bias, float* __restrict__ out, const int S)
{
  const int idx = blockIdx.x * 256 + threadIdx.x;
  const int i  = idx >> 5;
  const int hc = (idx & 31) * 4;
  const int h  = hc >> 6;
  float4 s; s.x = s.y = s.z = s.w = 0.f;
  float d = 0.f;
  for (int sp = 0; sp < S; ++sp) {
    float4 v = *(const float4*)(part + ((size_t)sp * NN + i) * 128 + hc);
    s.x += v.x; s.y += v.y; s.z += v.z; s.w += v.w;
    d += denp[((size_t)sp * NN + i) * 2 + h];
  }
  const float sc = 1.f / (d + 0.001f);
  float4 bv = *(const float4*)(bias + hc);
  float4 o;
  o.x = s.x * sc + bv.x;
  o.y = s.y * sc + bv.y;
  o.z = s.z * sc + bv.z;
  o.w = s.w * sc + bv.w;
  *(float4*)(out + (size_t)i * 128 + hc) = o;
}

extern "C" void kernel_launch(void* const* d_in, const int* in_sizes, int n_in,
                              void* d_out, int out_size, void* d_ws, size_t ws_size,
                              hipStream_t stream) {
  const float* A    = (const float*)d_in[0];
  const float* X    = (const float*)d_in[1];
  const float* W    = (const float*)d_in[2];
  const float* attn = (const float*)d_in[3];
  const float* bias = (const float*)d_in[4];
  float* out = (float*)d_out;

  char* ws = (char*)d_ws;
  size_t off = 0;
  ushort_t* XpT = (ushort_t*)(ws + off); off += (size_t)128 * NN * sizeof(ushort_t);
  float* x0g = (float*)(ws + off); off += (size_t)NN * 2 * sizeof(float);
  float* x1g = (float*)(ws + off); off += (size_t)2 * NN * sizeof(float);

  int S = 4;
  while (S > 1) {
    size_t need = off + (size_t)S * NN * 2 * 4 + (size_t)S * NN * 128 * 4;
    if (need <= ws_size) break;
    S >>= 1;
  }
  float* denp = (float*)(ws + off); off += (size_t)S * NN * 2 * sizeof(float);
  float* part = (float*)(ws + off);
  const int KS = NN / S;

  k1_project<<<256, 256, 0, stream>>>(X, W, attn, XpT, x0g, x1g);
  k2_main<<<256 * S, 256, 0, stream>>>(A, XpT, x0g, x1g, part, denp, S, KS);
  k3_finish<<<1024, 256, 0, stream>>>(part, denp, bias, out, S);
}